// Round 2
// baseline (3536.550 us; speedup 1.0000x reference)
//
#include <hip/hip_runtime.h>

// Problem constants
// N=8, T_y=300, T_x=160, E=256, E/2=128, 3E=768
// d_out: [attn 8*300*160 = 384000][outputs 8*300*256 = 614400][hidden 2048]

typedef _Float16 f16x2 __attribute__((ext_vector_type(2)));
typedef _Float16 f16x8 __attribute__((ext_vector_type(8)));

__device__ __forceinline__ float fexp2(float x) { return __builtin_amdgcn_exp2f(x); }
__device__ __forceinline__ float frcp(float x) { return __builtin_amdgcn_rcpf(x); }
// sigmoid(x) = 1/(1+2^(-x*log2 e))
__device__ __forceinline__ float fsig(float x) {
    return frcp(1.0f + fexp2(x * -1.4426950408889634f));
}
// tanh(y) = 1 - 2/(1+2^(y*2*log2 e)); saturates correctly at +-inf args
__device__ __forceinline__ float ftanh(float x) {
    return 1.0f - 2.0f * frcp(1.0f + fexp2(x * 2.8853900817779268f));
}

__device__ __forceinline__ f16x2 bc_h2(unsigned u) {
    union { unsigned u; f16x2 h; } cv;
    cv.u = u;
    return cv.h;
}

// ---------------------------------------------------------------------------
// Kernel A: repack Whh (f32 [768][256]) into per-thread v_dot2 weight order.
// gru thread t (of 512), pair p=t>>1, odd=t&1 owns rows {3p,3p+1,3p+2} over
// k-half [odd*128, odd*128+128). Consumption order i = cp*12 + rr*4 + m,
// cp in [0,16): chunk of 8 f16 at k = 8*(cp+16*odd); m indexes the 4 f16x2
// of the chunk. wd layout [i*512 + t] so the one-time gru load is coalesced.
// ---------------------------------------------------------------------------
__global__ __launch_bounds__(256) void prep_wd(const float* __restrict__ Whh,
                                               unsigned* __restrict__ wd) {
    int gid = blockIdx.x * 256 + threadIdx.x;   // 0..98303 = 192*512
    int i = gid >> 9, t = gid & 511;
    int p = t >> 1, odd = t & 1;
    int cp = i / 12, rem = i - cp * 12;
    int rr = rem >> 2, m = rem & 3;
    int row = 3 * p + rr;
    int k = 8 * (cp + 16 * odd) + 2 * m;
    union { unsigned u; f16x2 h; } cv;
    cv.h[0] = (_Float16)Whh[(size_t)row * 256 + k];
    cv.h[1] = (_Float16)Whh[(size_t)row * 256 + k + 1];
    wd[i * 512 + t] = cv.u;
}

// ---------------------------------------------------------------------------
// Kernel B: generic f32 tiled GEMM  C[M,N] = X[M,K] @ Wt[N,K]^T
// mode 0: C f32 natural [row*N+col]
// mode 1: gi scatter: row=(b*300+t) -> store at (t*8+b)*768+col, bias folded
//         (bih+bhh for r,z gates; bih only for n gate)
// mode 2: C16 f16 natural
// BM=BN=64, BK=32, 256 threads, 4x4 per thread.
// ---------------------------------------------------------------------------
__global__ __launch_bounds__(256) void gemm_kernel(
    const float* __restrict__ X, const float* __restrict__ Wt,
    float* __restrict__ C, _Float16* __restrict__ C16,
    const float* __restrict__ bih, const float* __restrict__ bhh,
    int M, int N, int K, int mode) {
    __shared__ float Xs[32][65];
    __shared__ float Ws2[32][65];
    const int n0 = blockIdx.x * 64, m0 = blockIdx.y * 64;
    const int tid = threadIdx.x;
    const int tx = tid & 15, ty = tid >> 4;
    float acc[4][4] = {};
    for (int k0 = 0; k0 < K; k0 += 32) {
#pragma unroll
        for (int i = 0; i < 8; ++i) {
            int e = tid + i * 256;
            int kk = e & 31, m = e >> 5;
            int row = m0 + m;
            Xs[kk][m] = (row < M) ? X[(size_t)row * K + k0 + kk] : 0.0f;
            Ws2[kk][m] = Wt[(size_t)(n0 + m) * K + k0 + kk];
        }
        __syncthreads();
#pragma unroll
        for (int kk = 0; kk < 32; ++kk) {
            float a[4], b[4];
#pragma unroll
            for (int i = 0; i < 4; ++i) a[i] = Xs[kk][ty * 4 + i];
#pragma unroll
            for (int j = 0; j < 4; ++j) b[j] = Ws2[kk][tx * 4 + j];
#pragma unroll
            for (int i = 0; i < 4; ++i)
#pragma unroll
                for (int j = 0; j < 4; ++j) acc[i][j] += a[i] * b[j];
        }
        __syncthreads();
    }
#pragma unroll
    for (int i = 0; i < 4; ++i) {
        int row = m0 + ty * 4 + i;
        if (row >= M) continue;
#pragma unroll
        for (int j = 0; j < 4; ++j) {
            int col = n0 + tx * 4 + j;
            float val = acc[i][j];
            if (mode == 1) {
                int b = row / 300;
                int t = row - b * 300;
                val += (col < 512) ? (bih[col] + bhh[col]) : bih[col];
                C[(size_t)(t * 8 + b) * 768 + col] = val;
            } else if (mode == 2) {
                C16[(size_t)row * N + col] = (_Float16)val;
            } else {
                C[(size_t)row * N + col] = val;
            }
        }
    }
}

// ---------------------------------------------------------------------------
// Kernel C: GRU recurrence via v_dot2_f32_f16 (weights resident in VGPRs).
// 8 blocks (one per batch) x 512 threads. Thread t: 192 dot2/step on its
// 1.5 rows (k-half split across the lane pair), f32 accumulate. h f16
// double-buffered in LDS (broadcast reads); gh assembled in LDS f32[768];
// epilogue on threads 0..255. 2 barriers/step.
// Issue floor: 768x256 MACs / (256 MAC/cy/CU via dot2) = 768 cy/step.
// ---------------------------------------------------------------------------
__global__ __launch_bounds__(512, 1) void gru_kernel(
    const float* __restrict__ gi, const unsigned* __restrict__ wd,
    const float* __restrict__ h0, const float* __restrict__ bhh,
    float* __restrict__ outs, float* __restrict__ hid) {
    const int b = blockIdx.x;
    const int t = threadIdx.x;
    const int p = t >> 1;
    const int codd = (t & 1) * 16;

    __shared__ __align__(16) _Float16 hbuf[2][256];
    __shared__ float ghbuf[768];

    // One-time resident weight load (coalesced): 192 VGPRs/thread.
    unsigned w[192];
#pragma unroll
    for (int i = 0; i < 192; ++i) w[i] = wd[i * 512 + t];

    float h = 0.0f, bn = 0.0f;
    if (t < 256) {
        h = h0[b * 256 + t];
        bn = bhh[512 + t];   // bhh_n stays inside r*(.)
        hbuf[0][t] = (_Float16)h;
    }
    const float* gp = gi + b * 768;
    float* op = outs + (size_t)b * 76800 + t;
    __syncthreads();

    for (int st = 0; st < 300; ++st) {
        // gi prefetch (independent of dot2 chain; scheduled early)
        float gr = 0.0f, gz = 0.0f, gn = 0.0f;
        if (t < 256) {
            const float* g = gp + (size_t)st * 6144 + t;
            gr = g[0];
            gz = g[256];
            gn = g[512];
        }
        const _Float16* hb = hbuf[st & 1];
        float a00 = 0.f, a01 = 0.f, a10 = 0.f, a11 = 0.f, a20 = 0.f, a21 = 0.f;
#pragma unroll 4
        for (int cp = 0; cp < 16; ++cp) {
            f16x8 hv = *(const f16x8*)(hb + (cp + codd) * 8);  // 2-addr broadcast
            f16x2 h20 = {hv[0], hv[1]}, h21 = {hv[2], hv[3]};
            f16x2 h22 = {hv[4], hv[5]}, h23 = {hv[6], hv[7]};
            const int base = cp * 12;
            a00 = __builtin_amdgcn_fdot2(bc_h2(w[base + 0]), h20, a00, false);
            a01 = __builtin_amdgcn_fdot2(bc_h2(w[base + 1]), h21, a01, false);
            a00 = __builtin_amdgcn_fdot2(bc_h2(w[base + 2]), h22, a00, false);
            a01 = __builtin_amdgcn_fdot2(bc_h2(w[base + 3]), h23, a01, false);
            a10 = __builtin_amdgcn_fdot2(bc_h2(w[base + 4]), h20, a10, false);
            a11 = __builtin_amdgcn_fdot2(bc_h2(w[base + 5]), h21, a11, false);
            a10 = __builtin_amdgcn_fdot2(bc_h2(w[base + 6]), h22, a10, false);
            a11 = __builtin_amdgcn_fdot2(bc_h2(w[base + 7]), h23, a11, false);
            a20 = __builtin_amdgcn_fdot2(bc_h2(w[base + 8]), h20, a20, false);
            a21 = __builtin_amdgcn_fdot2(bc_h2(w[base + 9]), h21, a21, false);
            a20 = __builtin_amdgcn_fdot2(bc_h2(w[base + 10]), h22, a20, false);
            a21 = __builtin_amdgcn_fdot2(bc_h2(w[base + 11]), h23, a21, false);
        }
        // Combine k-halves across the lane pair; write gh rows.
        float s0 = a00 + a01;
        float s1 = a10 + a11;
        float s2 = a20 + a21;
        s0 += __shfl_xor(s0, 1);
        s1 += __shfl_xor(s1, 1);
        s2 += __shfl_xor(s2, 1);
        if (!(t & 1)) {
            ghbuf[3 * p] = s0;
            ghbuf[3 * p + 1] = s1;
        } else {
            ghbuf[3 * p + 2] = s2;
        }
        __syncthreads();
        if (t < 256) {
            float r = fsig(gr + ghbuf[t]);
            float z = fsig(gz + ghbuf[256 + t]);
            float n = ftanh(gn + r * (ghbuf[512 + t] + bn));
            h = n + z * (h - n);
            op[st * 256] = h;
            hbuf[(st + 1) & 1][t] = (_Float16)h;
        }
        __syncthreads();
    }
    if (t < 256) hid[b * 256 + t] = h;
}

// ---------------------------------------------------------------------------
// Kernel D: scores + softmax. Block = (t-chunk of 10, batch). Threads 0..159
// each own one x; u read as f16 from ws, w-row and v staged in LDS.
// ---------------------------------------------------------------------------
__global__ __launch_bounds__(256) void attn_kernel(
    const _Float16* __restrict__ u16, const float* __restrict__ wv,
    const float* __restrict__ v, float* __restrict__ attn) {
    const int tc = blockIdx.x, b = blockIdx.y;
    const int tid = threadIdx.x;
    __shared__ float wL[256], vL[256], sc[160], red[2];
    vL[tid] = v[tid];
    for (int ti = 0; ti < 10; ++ti) {
        int t = tc * 10 + ti;
        wL[tid] = wv[(size_t)(b * 300 + t) * 256 + tid];
        __syncthreads();
        float acc = 0.0f;
        if (tid < 160) {
            const uint32_t* ur = (const uint32_t*)(u16 + (size_t)(b * 160 + tid) * 256);
#pragma unroll 8
            for (int e2 = 0; e2 < 128; ++e2) {
                union { uint32_t uu; _Float16 hh[2]; } cv;
                cv.uu = ur[e2];
                int e = e2 * 2;
                acc += vL[e] * ftanh(wL[e] + (float)cv.hh[0]);
                acc += vL[e + 1] * ftanh(wL[e + 1] + (float)cv.hh[1]);
            }
            sc[tid] = acc;
        }
        __syncthreads();
        if (tid < 64) {
            float m = -3.0e38f;
            for (int i = tid; i < 160; i += 64) m = fmaxf(m, sc[i]);
#pragma unroll
            for (int o = 32; o; o >>= 1) m = fmaxf(m, __shfl_xor(m, o));
            if (tid == 0) red[0] = m;
        }
        __syncthreads();
        float ee = 0.0f;
        if (tid < 160) {
            ee = fexp2((acc - red[0]) * 1.4426950408889634f);
            sc[tid] = ee;
        }
        __syncthreads();
        if (tid < 64) {
            float s = 0.0f;
            for (int i = tid; i < 160; i += 64) s += sc[i];
#pragma unroll
            for (int o = 32; o; o >>= 1) s += __shfl_xor(s, o);
            if (tid == 0) red[1] = s;
        }
        __syncthreads();
        if (tid < 160)
            attn[(size_t)(b * 300 + t) * 160 + tid] = ee * frcp(red[1]);
        __syncthreads();
    }
}

// ---------------------------------------------------------------------------
// ws layout (bytes):
//   [0, 7372800)        gi f32 [(t*8+b)*768 + col]           (live: K1b..gru)
//   [7372800, 7766016)  wd u32 dot2-weights [i*512+t]        (live: prep..gru)
//   [0, 655360)         u f16 [b*160+x][256]   (aliases dead gi, post-gru)
//   [655360, 3112960)   w f32 [b*300+t][256]   (aliases dead gi, post-gru)
// ---------------------------------------------------------------------------
extern "C" void kernel_launch(void* const* d_in, const int* in_sizes, int n_in,
                              void* d_out, int out_size, void* d_ws, size_t ws_size,
                              hipStream_t stream) {
    const float* inputs = (const float*)d_in[0];
    const float* memory = (const float*)d_in[1];
    const float* h0 = (const float*)d_in[2];
    const float* Wih = (const float*)d_in[3];
    const float* Whh = (const float*)d_in[4];
    const float* bih = (const float*)d_in[5];
    const float* bhh = (const float*)d_in[6];
    const float* Wm = (const float*)d_in[7];
    const float* Um = (const float*)d_in[8];
    const float* vv = (const float*)d_in[9];

    float* out = (float*)d_out;
    float* out_attn = out;              // 384000
    float* out_outputs = out + 384000;  // 614400
    float* out_hidden = out + 998400;   // 2048

    char* ws = (char*)d_ws;
    float* gi = (float*)ws;
    unsigned* wd = (unsigned*)(ws + 7372800);
    _Float16* u16 = (_Float16*)ws;
    float* wbuf = (float*)(ws + 655360);

    // Phase 1: weight repack + gi GEMM (bias-folded, scattered)
    prep_wd<<<384, 256, 0, stream>>>(Whh, wd);
    gemm_kernel<<<dim3(12, 38), 256, 0, stream>>>(inputs, Wih, gi, nullptr,
                                                  bih, bhh, 2400, 768, 128, 1);
    // Phase 2: sequential GRU (critical path, 8 CUs, weight-stationary dot2)
    gru_kernel<<<8, 512, 0, stream>>>(gi, wd, h0, bhh, out_outputs, out_hidden);
    // Phase 3: attention precompute + scores/softmax
    gemm_kernel<<<dim3(4, 20), 256, 0, stream>>>(memory, Um, nullptr, u16,
                                                 nullptr, nullptr, 1280, 256, 256, 2);
    gemm_kernel<<<dim3(4, 38), 256, 0, stream>>>(out_outputs, Wm, wbuf, nullptr,
                                                 nullptr, nullptr, 2400, 256, 256, 0);
    attn_kernel<<<dim3(30, 8), 256, 0, stream>>>(u16, wbuf, vv, out_attn);
}

// Round 3
// 584.951 us; speedup vs baseline: 6.0459x; 6.0459x over previous
//
#include <hip/hip_runtime.h>

// Problem constants
// N=8, T_y=300, T_x=160, E=256, E/2=128, 3E=768
// d_out: [attn 8*300*160 = 384000][outputs 8*300*256 = 614400][hidden 2048]

typedef _Float16 f16x2 __attribute__((ext_vector_type(2)));
typedef _Float16 f16x8 __attribute__((ext_vector_type(8)));

__device__ __forceinline__ float fexp2(float x) { return __builtin_amdgcn_exp2f(x); }
__device__ __forceinline__ float frcp(float x) { return __builtin_amdgcn_rcpf(x); }
// sigmoid(x) = 1/(1+2^(-x*log2 e))
__device__ __forceinline__ float fsig(float x) {
    return frcp(1.0f + fexp2(x * -1.4426950408889634f));
}
// tanh(y) = 1 - 2/(1+2^(y*2*log2 e)); saturates correctly at +-inf args
__device__ __forceinline__ float ftanh(float x) {
    return 1.0f - 2.0f * frcp(1.0f + fexp2(x * 2.8853900817779268f));
}

__device__ __forceinline__ f16x2 bc_h2(unsigned u) {
    union { unsigned u; f16x2 h; } cv;
    cv.u = u;
    return cv.h;
}

// ---------------------------------------------------------------------------
// Kernel A: repack Whh (f32 [768][256]) into per-thread v_dot2 weight order.
// gru thread t (of 512), pair p=t>>1, odd=t&1 owns rows {3p,3p+1,3p+2} over
// k-half [odd*128, odd*128+128). Consumption order i = cp*12 + rr*4 + m,
// cp in [0,16): chunk of 8 f16 at k = 8*(cp+16*odd); m indexes the 4 f16x2
// of the chunk. wd layout [i*512 + t] so the one-time gru load is coalesced.
// ---------------------------------------------------------------------------
__global__ __launch_bounds__(256) void prep_wd(const float* __restrict__ Whh,
                                               unsigned* __restrict__ wd) {
    int gid = blockIdx.x * 256 + threadIdx.x;   // 0..98303 = 192*512
    int i = gid >> 9, t = gid & 511;
    int p = t >> 1, odd = t & 1;
    int cp = i / 12, rem = i - cp * 12;
    int rr = rem >> 2, m = rem & 3;
    int row = 3 * p + rr;
    int k = 8 * (cp + 16 * odd) + 2 * m;
    union { unsigned u; f16x2 h; } cv;
    cv.h[0] = (_Float16)Whh[(size_t)row * 256 + k];
    cv.h[1] = (_Float16)Whh[(size_t)row * 256 + k + 1];
    wd[i * 512 + t] = cv.u;
}

// ---------------------------------------------------------------------------
// Kernel B: generic f32 tiled GEMM  C[M,N] = X[M,K] @ Wt[N,K]^T
// mode 0: C f32 natural [row*N+col]
// mode 1: gi scatter: row=(b*300+t) -> store at (t*8+b)*768+col, bias folded
//         (bih+bhh for r,z gates; bih only for n gate)
// mode 2: C16 f16 natural
// BM=BN=64, BK=32, 256 threads, 4x4 per thread.
// ---------------------------------------------------------------------------
__global__ __launch_bounds__(256) void gemm_kernel(
    const float* __restrict__ X, const float* __restrict__ Wt,
    float* __restrict__ C, _Float16* __restrict__ C16,
    const float* __restrict__ bih, const float* __restrict__ bhh,
    int M, int N, int K, int mode) {
    __shared__ float Xs[32][65];
    __shared__ float Ws2[32][65];
    const int n0 = blockIdx.x * 64, m0 = blockIdx.y * 64;
    const int tid = threadIdx.x;
    const int tx = tid & 15, ty = tid >> 4;
    float acc[4][4] = {};
    for (int k0 = 0; k0 < K; k0 += 32) {
#pragma unroll
        for (int i = 0; i < 8; ++i) {
            int e = tid + i * 256;
            int kk = e & 31, m = e >> 5;
            int row = m0 + m;
            Xs[kk][m] = (row < M) ? X[(size_t)row * K + k0 + kk] : 0.0f;
            Ws2[kk][m] = Wt[(size_t)(n0 + m) * K + k0 + kk];
        }
        __syncthreads();
#pragma unroll
        for (int kk = 0; kk < 32; ++kk) {
            float a[4], b[4];
#pragma unroll
            for (int i = 0; i < 4; ++i) a[i] = Xs[kk][ty * 4 + i];
#pragma unroll
            for (int j = 0; j < 4; ++j) b[j] = Ws2[kk][tx * 4 + j];
#pragma unroll
            for (int i = 0; i < 4; ++i)
#pragma unroll
                for (int j = 0; j < 4; ++j) acc[i][j] += a[i] * b[j];
        }
        __syncthreads();
    }
#pragma unroll
    for (int i = 0; i < 4; ++i) {
        int row = m0 + ty * 4 + i;
        if (row >= M) continue;
#pragma unroll
        for (int j = 0; j < 4; ++j) {
            int col = n0 + tx * 4 + j;
            float val = acc[i][j];
            if (mode == 1) {
                int b = row / 300;
                int t = row - b * 300;
                val += (col < 512) ? (bih[col] + bhh[col]) : bih[col];
                C[(size_t)(t * 8 + b) * 768 + col] = val;
            } else if (mode == 2) {
                C16[(size_t)row * N + col] = (_Float16)val;
            } else {
                C[(size_t)row * N + col] = val;
            }
        }
    }
}

// ---------------------------------------------------------------------------
// Kernel C: GRU recurrence via v_dot2_f32_f16 (weights resident in VGPRs).
// 8 blocks (one per batch) x 512 threads. Thread t: 192 dot2/step on its
// 1.5 rows (k-half split across the lane pair), f32 accumulate. h f16
// double-buffered in LDS (broadcast reads); gh assembled in LDS f32[768];
// epilogue on threads 0..255. 2 barriers/step.
// CRITICAL: cp loop must be FULLY unrolled so every w[...] index is a
// compile-time constant -> SROA keeps all 192 weights in VGPRs. A partial
// unroll leaves runtime indices -> whole array spills to scratch (round 2:
// VGPR_Count 44, 3.3 ms).
// Issue floor: 768x256 MACs / (256 MAC/cy/CU via dot2) = 768 cy/step.
// ---------------------------------------------------------------------------
__global__ __launch_bounds__(512, 1) void gru_kernel(
    const float* __restrict__ gi, const unsigned* __restrict__ wd,
    const float* __restrict__ h0, const float* __restrict__ bhh,
    float* __restrict__ outs, float* __restrict__ hid) {
    const int b = blockIdx.x;
    const int t = threadIdx.x;
    const int p = t >> 1;
    const int codd = (t & 1) * 16;

    __shared__ __align__(16) _Float16 hbuf[2][256];
    __shared__ float ghbuf[768];

    // One-time resident weight load (coalesced): 192 VGPRs/thread.
    unsigned w[192];
#pragma unroll
    for (int i = 0; i < 192; ++i) w[i] = wd[i * 512 + t];

    float h = 0.0f, bn = 0.0f;
    if (t < 256) {
        h = h0[b * 256 + t];
        bn = bhh[512 + t];   // bhh_n stays inside r*(.)
        hbuf[0][t] = (_Float16)h;
    }
    const float* gp = gi + b * 768;
    float* op = outs + (size_t)b * 76800 + t;
    __syncthreads();

    for (int st = 0; st < 300; ++st) {
        // gi prefetch (independent of dot2 chain; scheduled early)
        float gr = 0.0f, gz = 0.0f, gn = 0.0f;
        if (t < 256) {
            const float* g = gp + (size_t)st * 6144 + t;
            gr = g[0];
            gz = g[256];
            gn = g[512];
        }
        const _Float16* hb = hbuf[st & 1];
        float a00 = 0.f, a01 = 0.f, a10 = 0.f, a11 = 0.f, a20 = 0.f, a21 = 0.f;
#pragma unroll
        for (int cp = 0; cp < 16; ++cp) {
            f16x8 hv = *(const f16x8*)(hb + (cp + codd) * 8);  // 2-addr broadcast
            f16x2 h20 = {hv[0], hv[1]}, h21 = {hv[2], hv[3]};
            f16x2 h22 = {hv[4], hv[5]}, h23 = {hv[6], hv[7]};
            a00 = __builtin_amdgcn_fdot2(bc_h2(w[cp * 12 + 0]), h20, a00, false);
            a01 = __builtin_amdgcn_fdot2(bc_h2(w[cp * 12 + 1]), h21, a01, false);
            a00 = __builtin_amdgcn_fdot2(bc_h2(w[cp * 12 + 2]), h22, a00, false);
            a01 = __builtin_amdgcn_fdot2(bc_h2(w[cp * 12 + 3]), h23, a01, false);
            a10 = __builtin_amdgcn_fdot2(bc_h2(w[cp * 12 + 4]), h20, a10, false);
            a11 = __builtin_amdgcn_fdot2(bc_h2(w[cp * 12 + 5]), h21, a11, false);
            a10 = __builtin_amdgcn_fdot2(bc_h2(w[cp * 12 + 6]), h22, a10, false);
            a11 = __builtin_amdgcn_fdot2(bc_h2(w[cp * 12 + 7]), h23, a11, false);
            a20 = __builtin_amdgcn_fdot2(bc_h2(w[cp * 12 + 8]), h20, a20, false);
            a21 = __builtin_amdgcn_fdot2(bc_h2(w[cp * 12 + 9]), h21, a21, false);
            a20 = __builtin_amdgcn_fdot2(bc_h2(w[cp * 12 + 10]), h22, a20, false);
            a21 = __builtin_amdgcn_fdot2(bc_h2(w[cp * 12 + 11]), h23, a21, false);
        }
        // Combine k-halves across the lane pair; write gh rows.
        float s0 = a00 + a01;
        float s1 = a10 + a11;
        float s2 = a20 + a21;
        s0 += __shfl_xor(s0, 1);
        s1 += __shfl_xor(s1, 1);
        s2 += __shfl_xor(s2, 1);
        if (!(t & 1)) {
            ghbuf[3 * p] = s0;
            ghbuf[3 * p + 1] = s1;
        } else {
            ghbuf[3 * p + 2] = s2;
        }
        __syncthreads();
        if (t < 256) {
            float r = fsig(gr + ghbuf[t]);
            float z = fsig(gz + ghbuf[256 + t]);
            float n = ftanh(gn + r * (ghbuf[512 + t] + bn));
            h = n + z * (h - n);
            op[st * 256] = h;
            hbuf[(st + 1) & 1][t] = (_Float16)h;
        }
        __syncthreads();
    }
    if (t < 256) hid[b * 256 + t] = h;
}

// ---------------------------------------------------------------------------
// Kernel D: scores + softmax. Block = (t-chunk of 10, batch). Threads 0..159
// each own one x; u read as f16 from ws, w-row and v staged in LDS.
// ---------------------------------------------------------------------------
__global__ __launch_bounds__(256) void attn_kernel(
    const _Float16* __restrict__ u16, const float* __restrict__ wv,
    const float* __restrict__ v, float* __restrict__ attn) {
    const int tc = blockIdx.x, b = blockIdx.y;
    const int tid = threadIdx.x;
    __shared__ float wL[256], vL[256], sc[160], red[2];
    vL[tid] = v[tid];
    for (int ti = 0; ti < 10; ++ti) {
        int t = tc * 10 + ti;
        wL[tid] = wv[(size_t)(b * 300 + t) * 256 + tid];
        __syncthreads();
        float acc = 0.0f;
        if (tid < 160) {
            const uint32_t* ur = (const uint32_t*)(u16 + (size_t)(b * 160 + tid) * 256);
#pragma unroll 8
            for (int e2 = 0; e2 < 128; ++e2) {
                union { uint32_t uu; _Float16 hh[2]; } cv;
                cv.uu = ur[e2];
                int e = e2 * 2;
                acc += vL[e] * ftanh(wL[e] + (float)cv.hh[0]);
                acc += vL[e + 1] * ftanh(wL[e + 1] + (float)cv.hh[1]);
            }
            sc[tid] = acc;
        }
        __syncthreads();
        if (tid < 64) {
            float m = -3.0e38f;
            for (int i = tid; i < 160; i += 64) m = fmaxf(m, sc[i]);
#pragma unroll
            for (int o = 32; o; o >>= 1) m = fmaxf(m, __shfl_xor(m, o));
            if (tid == 0) red[0] = m;
        }
        __syncthreads();
        float ee = 0.0f;
        if (tid < 160) {
            ee = fexp2((acc - red[0]) * 1.4426950408889634f);
            sc[tid] = ee;
        }
        __syncthreads();
        if (tid < 64) {
            float s = 0.0f;
            for (int i = tid; i < 160; i += 64) s += sc[i];
#pragma unroll
            for (int o = 32; o; o >>= 1) s += __shfl_xor(s, o);
            if (tid == 0) red[1] = s;
        }
        __syncthreads();
        if (tid < 160)
            attn[(size_t)(b * 300 + t) * 160 + tid] = ee * frcp(red[1]);
        __syncthreads();
    }
}

// ---------------------------------------------------------------------------
// ws layout (bytes):
//   [0, 7372800)        gi f32 [(t*8+b)*768 + col]           (live: K1b..gru)
//   [7372800, 7766016)  wd u32 dot2-weights [i*512+t]        (live: prep..gru)
//   [0, 655360)         u f16 [b*160+x][256]   (aliases dead gi, post-gru)
//   [655360, 3112960)   w f32 [b*300+t][256]   (aliases dead gi, post-gru)
// ---------------------------------------------------------------------------
extern "C" void kernel_launch(void* const* d_in, const int* in_sizes, int n_in,
                              void* d_out, int out_size, void* d_ws, size_t ws_size,
                              hipStream_t stream) {
    const float* inputs = (const float*)d_in[0];
    const float* memory = (const float*)d_in[1];
    const float* h0 = (const float*)d_in[2];
    const float* Wih = (const float*)d_in[3];
    const float* Whh = (const float*)d_in[4];
    const float* bih = (const float*)d_in[5];
    const float* bhh = (const float*)d_in[6];
    const float* Wm = (const float*)d_in[7];
    const float* Um = (const float*)d_in[8];
    const float* vv = (const float*)d_in[9];

    float* out = (float*)d_out;
    float* out_attn = out;              // 384000
    float* out_outputs = out + 384000;  // 614400
    float* out_hidden = out + 998400;   // 2048

    char* ws = (char*)d_ws;
    float* gi = (float*)ws;
    unsigned* wd = (unsigned*)(ws + 7372800);
    _Float16* u16 = (_Float16*)ws;
    float* wbuf = (float*)(ws + 655360);

    // Phase 1: weight repack + gi GEMM (bias-folded, scattered)
    prep_wd<<<384, 256, 0, stream>>>(Whh, wd);
    gemm_kernel<<<dim3(12, 38), 256, 0, stream>>>(inputs, Wih, gi, nullptr,
                                                  bih, bhh, 2400, 768, 128, 1);
    // Phase 2: sequential GRU (critical path, 8 CUs, weight-stationary dot2)
    gru_kernel<<<8, 512, 0, stream>>>(gi, wd, h0, bhh, out_outputs, out_hidden);
    // Phase 3: attention precompute + scores/softmax
    gemm_kernel<<<dim3(4, 20), 256, 0, stream>>>(memory, Um, nullptr, u16,
                                                 nullptr, nullptr, 1280, 256, 256, 2);
    gemm_kernel<<<dim3(4, 38), 256, 0, stream>>>(out_outputs, Wm, wbuf, nullptr,
                                                 nullptr, nullptr, 2400, 256, 256, 0);
    attn_kernel<<<dim3(30, 8), 256, 0, stream>>>(u16, wbuf, vv, out_attn);
}